// Round 9
// baseline (225.383 us; speedup 1.0000x reference)
//
#include <hip/hip_runtime.h>

#define BDIM 256
#define KC_STRIDE 28                  // per (case,co): K[0..24], bias at [25], 2 pad
#define CASE_STRIDE (32 * KC_STRIDE)  // 896 floats per border-case
#define SP 1032                       // S plane stride (16 rows x 64 + 8 pad)

// case index along one axis: 0 (p==0), 1 (p==1), 2 (interior), 3 (p==62), 4 (p==63)
__device__ __forceinline__ int casef(int p) {
  return ((unsigned)(p - 2) < 60u) ? 2 : (p < 2 ? p : p - 59);
}

// ---------------- prep: collapsed 5x5 kernels, layout [case][co][28] ----------------
__global__ __launch_bounds__(BDIM) void prep_kernel(
    const float* __restrict__ W1, const float* __restrict__ b1,
    const float* __restrict__ W2, const float* __restrict__ b2,
    float* __restrict__ ws) {
  __shared__ float Mlds[9 * 9 * 32];
  __shared__ float BvL[9 * 32];
  const int tid = threadIdx.x;
  const int co = tid & 31;
  for (int tap = tid >> 5; tap < 9; tap += 8) {
    float acc[9] = {0.f, 0.f, 0.f, 0.f, 0.f, 0.f, 0.f, 0.f, 0.f};
    float accB = 0.f;
    for (int ci = 0; ci < 64; ++ci) {
      float w2 = W2[(tap * 64 + ci) * 32 + co];
      accB = fmaf(b1[ci], w2, accB);
#pragma unroll
      for (int e = 0; e < 9; ++e) acc[e] = fmaf(W1[e * 64 + ci], w2, acc[e]);
    }
#pragma unroll
    for (int e = 0; e < 9; ++e) Mlds[(tap * 9 + e) * 32 + co] = acc[e];
    BvL[tap * 32 + co] = accB;
  }
  __syncthreads();

  const int a = blockIdx.x / 5, c = blockIdx.x % 5;
  const int dmask[5] = {4, 6, 7, 3, 1};
  const int Da = dmask[a], Dc = dmask[c];
  for (int t = tid; t < CASE_STRIDE; t += BDIM) {
    int cc = t / KC_STRIDE, r = t % KC_STRIDE;
    float s = 0.f;
    if (r < 25) {
      int u = r / 5, v = r % 5;
      for (int di = 0; di < 3; ++di) {
        if (!((Da >> di) & 1)) continue;
        int ei = u - di;
        if ((unsigned)ei > 2u) continue;
        for (int dj = 0; dj < 3; ++dj) {
          if (!((Dc >> dj) & 1)) continue;
          int ej = v - dj;
          if ((unsigned)ej > 2u) continue;
          s += Mlds[((di * 3 + dj) * 9 + ei * 3 + ej) * 32 + cc];
        }
      }
    } else if (r == 25) {
      s = b2[cc];
      for (int di = 0; di < 3; ++di)
        if ((Da >> di) & 1)
          for (int dj = 0; dj < 3; ++dj)
            if ((Dc >> dj) & 1) s += BvL[(di * 3 + dj) * 32 + cc];
    }
    ws[blockIdx.x * CASE_STRIDE + t] = s;
  }
}

// ---- main: R3 skeleton + lane-static co4 (K hoisted to VGPR) + co-pairing ----
__global__ __launch_bounds__(BDIM) void main_kernel(
    const float* __restrict__ x, const float* __restrict__ ws,
    float* __restrict__ out) {
  const int bb = blockIdx.x;
  const int b = bb >> 1;
  const int r0 = (bb & 1) << 5;  // 0 or 32
  const int tid = threadIdx.x;
  const int lane = tid & 63;
  const int wave = tid >> 6;

  __shared__ __align__(16) float xp[36 * 68];       // rows r0-2..r0+33, cols -2..65
  __shared__ __align__(16) float S[8 * SP];         // 8 planes of 16x64 (+pad)
  __shared__ __align__(16) float KiL[CASE_STRIDE];  // interior case (2,2)
  __shared__ unsigned long long Rm[32];
  __shared__ unsigned short aqi[2][224], aqb[2][64];
  __shared__ int nqi_sh[2], nqb_sh[2];

  if (tid < 2) { nqi_sh[tid] = 0; nqb_sh[tid] = 0; }
  float4* xp4 = reinterpret_cast<float4*>(xp);
  for (int i = tid; i < 612; i += BDIM) xp4[i] = make_float4(0.f, 0.f, 0.f, 0.f);
  for (int i = tid; i < CASE_STRIDE; i += BDIM) KiL[i] = ws[12 * CASE_STRIDE + i];
  __syncthreads();

  const float* xb = x + (size_t)b * 4096;
  for (int it = tid; it < 576; it += BDIM) {
    int i = it >> 4, c4 = (it & 15) << 2;
    int r = r0 - 2 + i;
    if ((unsigned)r < 64u) {
      float4 v = *reinterpret_cast<const float4*>(xb + r * 64 + c4);
      float2* d2 = reinterpret_cast<float2*>(&xp[i * 68 + 2 + c4]);
      d2[0] = make_float2(v.x, v.y);
      d2[1] = make_float2(v.z, v.w);
    }
  }
  __syncthreads();

  for (int k = wave; k < 32; k += 4) {
    int pred = (xp[(k + 2) * 68 + 2 + lane] != 0.0f);
    unsigned long long m = __ballot(pred);
    if (lane == 0) Rm[k] = m;
  }
  __syncthreads();

  for (int g = tid; g < 512; g += BDIM) {
    int k = g >> 4, q0 = (g & 15) << 2;
    unsigned bits = (unsigned)(Rm[k] >> q0) & 0xFu;
    if (!bits) continue;
    int h = k >> 4;
    int p = r0 + k;
    bool inter = ((unsigned)(p - 2) < 60u) && ((unsigned)(q0 - 4) <= 52u);
    if (inter) {
      aqi[h][atomicAdd(&nqi_sh[h], 1)] = (unsigned short)g;
    } else {
      aqb[h][atomicAdd(&nqb_sh[h], 1)] = (unsigned short)g;
    }
  }
  __syncthreads();

  const int ni0 = nqi_sh[0], ni1 = nqi_sh[1];
  const int nb0 = nqb_sh[0], nb1 = nqb_sh[1];
  float* outb = out + (size_t)b * (32 * 4096);
  const int co4 = tid & 3;

  for (int sg = 0; sg < 4; ++sg) {
    const int co_lo = (sg << 2) + co4;  // lane-static per stage
    const int co_hi = co_lo + 16;
    // hoisted interior kernels -> VGPRs (broadcast LDS reads, once per stage)
    float KA[26], KB[26];
#pragma unroll
    for (int j = 0; j < 26; ++j) KA[j] = KiL[co_lo * KC_STRIDE + j];
#pragma unroll
    for (int j = 0; j < 26; ++j) KB[j] = KiL[co_hi * KC_STRIDE + j];

    for (int h = 0; h < 2; ++h) {
      const int ni = h ? ni1 : ni0;
      const int nb = h ? nb1 : nb0;
      // ---- interior: item = (quad, co4-pair); co4 = tid&3 constant ----
      for (int n = tid; n < ni * 4; n += BDIM) {
        int g = aqi[h][n >> 2];
        int k = g >> 4, q0 = (g & 15) << 2;
        float za0 = KA[25], za1 = KA[25], za2 = KA[25], za3 = KA[25];
        float zb0 = KB[25], zb1 = KB[25], zb2 = KB[25], zb3 = KB[25];
#pragma unroll
        for (int u = 0; u < 5; ++u) {
          const float* xr = &xp[(k + u) * 68 + q0];
          float4 xa = *reinterpret_cast<const float4*>(xr);
          float4 xc = *reinterpret_cast<const float4*>(xr + 4);
          float xv[8] = {xa.x, xa.y, xa.z, xa.w, xc.x, xc.y, xc.z, xc.w};
#pragma unroll
          for (int v = 0; v < 5; ++v) {
            float ka = KA[u * 5 + v], kb = KB[u * 5 + v];
            za0 = fmaf(xv[v], ka, za0);
            za1 = fmaf(xv[v + 1], ka, za1);
            za2 = fmaf(xv[v + 2], ka, za2);
            za3 = fmaf(xv[v + 3], ka, za3);
            zb0 = fmaf(xv[v], kb, zb0);
            zb1 = fmaf(xv[v + 1], kb, zb1);
            zb2 = fmaf(xv[v + 2], kb, zb2);
            zb3 = fmaf(xv[v + 3], kb, zb3);
          }
        }
        int so = ((k & 15) << 6) + q0;
        *reinterpret_cast<float4*>(&S[co4 * SP + so]) = make_float4(za0, za1, za2, za3);
        *reinterpret_cast<float4*>(&S[(co4 + 4) * SP + so]) = make_float4(zb0, zb1, zb2, zb3);
      }
      // ---- border: item = (quad, co_sel of 8); per-pixel case, K from L2 ----
      for (int n = tid; n < nb * 8; n += BDIM) {
        int g = aqb[h][n >> 3];
        int cs = tid & 7;
        int co = (sg << 2) + (cs & 3) + ((cs >> 2) << 4);
        int k = g >> 4, q0 = (g & 15) << 2;
        int p = r0 + k;
        int cp = casef(p);
        const float* K0 = ws + ((cp * 5 + casef(q0)) * 32 + co) * KC_STRIDE;
        const float* K1 = ws + ((cp * 5 + casef(q0 + 1)) * 32 + co) * KC_STRIDE;
        const float* K2 = ws + ((cp * 5 + casef(q0 + 2)) * 32 + co) * KC_STRIDE;
        const float* K3 = ws + ((cp * 5 + casef(q0 + 3)) * 32 + co) * KC_STRIDE;
        float z0 = K0[25], z1 = K1[25], z2 = K2[25], z3 = K3[25];
#pragma unroll
        for (int u = 0; u < 5; ++u) {
          const float* xr = &xp[(k + u) * 68 + q0];
          float4 xa = *reinterpret_cast<const float4*>(xr);
          float4 xc = *reinterpret_cast<const float4*>(xr + 4);
          float xv[8] = {xa.x, xa.y, xa.z, xa.w, xc.x, xc.y, xc.z, xc.w};
#pragma unroll
          for (int v = 0; v < 5; ++v) {
            int o = u * 5 + v;
            z0 = fmaf(xv[v], K0[o], z0);
            z1 = fmaf(xv[v + 1], K1[o], z1);
            z2 = fmaf(xv[v + 2], K2[o], z2);
            z3 = fmaf(xv[v + 3], K3[o], z3);
          }
        }
        *reinterpret_cast<float4*>(&S[cs * SP + ((k & 15) << 6) + q0]) =
            make_float4(z0, z1, z2, z3);
      }
      // ---- LDS-visibility barrier (stores stay in flight) ----
      asm volatile("s_waitcnt lgkmcnt(0)" ::: "memory");
      __builtin_amdgcn_s_barrier();
      // ---- dump: wave w -> planes w (co_lo) and w+4 (co_hi); mask here ----
      {
        int cw_lo = (sg << 2) + wave;
        float* dstA = outb + (((size_t)cw_lo) << 12) + ((r0 + (h << 4)) << 6);
        float* dstB = outb + (((size_t)(cw_lo + 16)) << 12) + ((r0 + (h << 4)) << 6);
#pragma unroll
        for (int i = 0; i < 4; ++i) {
          int f4 = (i << 6) + lane;
          int kk = f4 >> 4, q0 = (f4 & 15) << 2;
          unsigned bits = (unsigned)(Rm[(h << 4) + kk] >> q0) & 0xFu;
          float4 va = *reinterpret_cast<const float4*>(&S[wave * SP + (f4 << 2)]);
          float4 vb = *reinterpret_cast<const float4*>(&S[(wave + 4) * SP + (f4 << 2)]);
          if (!(bits & 1u)) { va.x = 0.f; vb.x = 0.f; }
          if (!(bits & 2u)) { va.y = 0.f; vb.y = 0.f; }
          if (!(bits & 4u)) { va.z = 0.f; vb.z = 0.f; }
          if (!(bits & 8u)) { va.w = 0.f; vb.w = 0.f; }
          *reinterpret_cast<float4*>(dstA + (f4 << 2)) = va;
          *reinterpret_cast<float4*>(dstB + (f4 << 2)) = vb;
        }
      }
      // ---- WAR barrier before next substage overwrites S ----
      asm volatile("s_waitcnt lgkmcnt(0)" ::: "memory");
      __builtin_amdgcn_s_barrier();
    }
  }
}

extern "C" void kernel_launch(void* const* d_in, const int* in_sizes, int n_in,
                              void* d_out, int out_size, void* d_ws, size_t ws_size,
                              hipStream_t stream) {
  const float* x  = (const float*)d_in[0];
  const float* W1 = (const float*)d_in[1];
  const float* b1 = (const float*)d_in[2];
  const float* W2 = (const float*)d_in[3];
  const float* b2 = (const float*)d_in[4];
  float* out = (float*)d_out;
  float* ws  = (float*)d_ws;
  int B = in_sizes[0] / 4096;  // 1024 images of 64x64x1

  hipLaunchKernelGGL(prep_kernel, dim3(25), dim3(BDIM), 0, stream, W1, b1, W2, b2, ws);
  hipLaunchKernelGGL(main_kernel, dim3(2 * B), dim3(BDIM), 0, stream, x, ws, out);
}

// Round 10
// 189.135 us; speedup vs baseline: 1.1917x; 1.1917x over previous
//
#include <hip/hip_runtime.h>

#define BDIM 256
#define KC_STRIDE 28                  // per (case,co): K[0..24], bias at [25], 2 pad
#define CASE_STRIDE (32 * KC_STRIDE)  // 896 floats per border-case
#define SP 1032                       // S plane stride (16 rows x 64 + 8 pad)

// case index along one axis: 0 (p==0), 1 (p==1), 2 (interior), 3 (p==62), 4 (p==63)
__device__ __forceinline__ int casef(int p) {
  return ((unsigned)(p - 2) < 60u) ? 2 : (p < 2 ? p : p - 59);
}

// ---------------- prep: collapsed 5x5 kernels, layout [case][co][28] ----------------
__global__ __launch_bounds__(BDIM) void prep_kernel(
    const float* __restrict__ W1, const float* __restrict__ b1,
    const float* __restrict__ W2, const float* __restrict__ b2,
    float* __restrict__ ws) {
  __shared__ float Mlds[9 * 9 * 32];
  __shared__ float BvL[9 * 32];
  const int tid = threadIdx.x;
  const int co = tid & 31;
  for (int tap = tid >> 5; tap < 9; tap += 8) {
    float acc[9] = {0.f, 0.f, 0.f, 0.f, 0.f, 0.f, 0.f, 0.f, 0.f};
    float accB = 0.f;
    for (int ci = 0; ci < 64; ++ci) {
      float w2 = W2[(tap * 64 + ci) * 32 + co];
      accB = fmaf(b1[ci], w2, accB);
#pragma unroll
      for (int e = 0; e < 9; ++e) acc[e] = fmaf(W1[e * 64 + ci], w2, acc[e]);
    }
#pragma unroll
    for (int e = 0; e < 9; ++e) Mlds[(tap * 9 + e) * 32 + co] = acc[e];
    BvL[tap * 32 + co] = accB;
  }
  __syncthreads();

  const int a = blockIdx.x / 5, c = blockIdx.x % 5;
  const int dmask[5] = {4, 6, 7, 3, 1};
  const int Da = dmask[a], Dc = dmask[c];
  for (int t = tid; t < CASE_STRIDE; t += BDIM) {
    int cc = t / KC_STRIDE, r = t % KC_STRIDE;
    float s = 0.f;
    if (r < 25) {
      int u = r / 5, v = r % 5;
      for (int di = 0; di < 3; ++di) {
        if (!((Da >> di) & 1)) continue;
        int ei = u - di;
        if ((unsigned)ei > 2u) continue;
        for (int dj = 0; dj < 3; ++dj) {
          if (!((Dc >> dj) & 1)) continue;
          int ej = v - dj;
          if ((unsigned)ej > 2u) continue;
          s += Mlds[((di * 3 + dj) * 9 + ei * 3 + ej) * 32 + cc];
        }
      }
    } else if (r == 25) {
      s = b2[cc];
      for (int di = 0; di < 3; ++di)
        if ((Da >> di) & 1)
          for (int dj = 0; dj < 3; ++dj)
            if ((Dc >> dj) & 1) s += BvL[(di * 3 + dj) * 32 + cc];
    }
    ws[blockIdx.x * CASE_STRIDE + t] = s;
  }
}

// ---- main: R6 compute structure + dbuf S + pipelined dump (dump(t-1) before
// ---- compute(t)), ONE lgkm-only barrier per substage, counted vmcnt pacing ----
__global__ __launch_bounds__(BDIM) void main_kernel(
    const float* __restrict__ x, const float* __restrict__ ws,
    float* __restrict__ out) {
  const int bb = blockIdx.x;
  const int b = bb >> 1;
  const int r0 = (bb & 1) << 5;  // 0 or 32
  const int tid = threadIdx.x;
  const int lane = tid & 63;
  const int wave = tid >> 6;

  __shared__ __align__(16) float xp[36 * 68];       // rows r0-2..r0+33, cols -2..65
  __shared__ __align__(16) float S[2][4][SP];       // dbuf x 4 planes of 16x64
  __shared__ __align__(16) float KiL[CASE_STRIDE];  // interior case (2,2)
  __shared__ unsigned long long Rm[32];
  __shared__ unsigned short aqi[2][224], aqb[2][64];
  __shared__ int nqi_sh[2], nqb_sh[2];

  if (tid < 2) { nqi_sh[tid] = 0; nqb_sh[tid] = 0; }
  float4* xp4 = reinterpret_cast<float4*>(xp);
  for (int i = tid; i < 612; i += BDIM) xp4[i] = make_float4(0.f, 0.f, 0.f, 0.f);
  for (int i = tid; i < CASE_STRIDE; i += BDIM) KiL[i] = ws[12 * CASE_STRIDE + i];
  __syncthreads();

  const float* xb = x + (size_t)b * 4096;
  for (int it = tid; it < 576; it += BDIM) {
    int i = it >> 4, c4 = (it & 15) << 2;
    int r = r0 - 2 + i;
    if ((unsigned)r < 64u) {
      float4 v = *reinterpret_cast<const float4*>(xb + r * 64 + c4);
      float2* d2 = reinterpret_cast<float2*>(&xp[i * 68 + 2 + c4]);
      d2[0] = make_float2(v.x, v.y);
      d2[1] = make_float2(v.z, v.w);
    }
  }
  __syncthreads();

  for (int k = wave; k < 32; k += 4) {
    int pred = (xp[(k + 2) * 68 + 2 + lane] != 0.0f);
    unsigned long long m = __ballot(pred);
    if (lane == 0) Rm[k] = m;
  }
  __syncthreads();

  for (int g = tid; g < 512; g += BDIM) {
    int k = g >> 4, q0 = (g & 15) << 2;
    unsigned bits = (unsigned)(Rm[k] >> q0) & 0xFu;
    if (!bits) continue;
    int h = k >> 4;
    int p = r0 + k;
    bool inter = ((unsigned)(p - 2) < 60u) && ((unsigned)(q0 - 4) <= 52u);
    if (inter) {
      aqi[h][atomicAdd(&nqi_sh[h], 1)] = (unsigned short)g;
    } else {
      aqb[h][atomicAdd(&nqb_sh[h], 1)] = (unsigned short)g;
    }
  }
  __syncthreads();

  const int ni0 = nqi_sh[0], ni1 = nqi_sh[1];
  const int nb0 = nqb_sh[0], nb1 = nqb_sh[1];
  float* outb = out + (size_t)b * (32 * 4096);

  // 16 substages: t -> (channel group cg = t>>1, row half h = t&1)
  for (int t = 0; t < 16; ++t) {
    const int cg = t >> 1, h = t & 1;
    // ---- dump(t-1): issue stores FIRST so they drain under this compute ----
    if (t > 0) {
      const int pt = t - 1;
      const int pcg = pt >> 1, ph = pt & 1;
      const int co = (pcg << 2) + wave;
      float* dst = outb + (((size_t)co) << 12) + ((r0 + (ph << 4)) << 6);
      const float4* Sp = reinterpret_cast<const float4*>(&S[pt & 1][wave][0]);
      asm volatile("s_waitcnt vmcnt(16)" ::: "memory");  // pace, never 0
#pragma unroll
      for (int i = 0; i < 4; ++i) {
        int f4 = (i << 6) + lane;
        int kk = f4 >> 4, q0 = (f4 & 15) << 2;
        unsigned bits = (unsigned)(Rm[(ph << 4) + kk] >> q0) & 0xFu;
        float4 v = Sp[f4];
        if (!(bits & 1u)) v.x = 0.f;
        if (!(bits & 2u)) v.y = 0.f;
        if (!(bits & 4u)) v.z = 0.f;
        if (!(bits & 8u)) v.w = 0.f;
        *reinterpret_cast<float4*>(dst + (f4 << 2)) = v;
      }
    }
    // ---- compute(t): interior quads, item = (quad, co4) ----
    const int ni = h ? ni1 : ni0;
    const int nb = h ? nb1 : nb0;
    float(*Sc)[SP] = S[t & 1];
    for (int n = tid; n < ni * 4; n += BDIM) {
      int g = aqi[h][n >> 2];
      int co4 = n & 3;
      int co = (cg << 2) + co4;
      int k = g >> 4, q0 = (g & 15) << 2;
      const float* Kp = &KiL[co * KC_STRIDE];
      float bias = Kp[25];
      float z0 = bias, z1 = bias, z2 = bias, z3 = bias;
#pragma unroll
      for (int u = 0; u < 5; ++u) {
        const float* xr = &xp[(k + u) * 68 + q0];
        float4 xa = *reinterpret_cast<const float4*>(xr);
        float4 xc = *reinterpret_cast<const float4*>(xr + 4);
        float xv[8] = {xa.x, xa.y, xa.z, xa.w, xc.x, xc.y, xc.z, xc.w};
#pragma unroll
        for (int v = 0; v < 5; ++v) {
          float Kv = Kp[u * 5 + v];
          z0 = fmaf(xv[v], Kv, z0);
          z1 = fmaf(xv[v + 1], Kv, z1);
          z2 = fmaf(xv[v + 2], Kv, z2);
          z3 = fmaf(xv[v + 3], Kv, z3);
        }
      }
      *reinterpret_cast<float4*>(&Sc[co4][((k & 15) << 6) + q0]) =
          make_float4(z0, z1, z2, z3);
    }
    // ---- compute(t): border quads, per-pixel case, K from global (L2-hot) ----
    for (int n = tid; n < nb * 4; n += BDIM) {
      int g = aqb[h][n >> 2];
      int co4 = n & 3;
      int co = (cg << 2) + co4;
      int k = g >> 4, q0 = (g & 15) << 2;
      int p = r0 + k;
      int cp = casef(p);
      const float* K0 = ws + ((cp * 5 + casef(q0)) * 32 + co) * KC_STRIDE;
      const float* K1 = ws + ((cp * 5 + casef(q0 + 1)) * 32 + co) * KC_STRIDE;
      const float* K2 = ws + ((cp * 5 + casef(q0 + 2)) * 32 + co) * KC_STRIDE;
      const float* K3 = ws + ((cp * 5 + casef(q0 + 3)) * 32 + co) * KC_STRIDE;
      float z0 = K0[25], z1 = K1[25], z2 = K2[25], z3 = K3[25];
#pragma unroll
      for (int u = 0; u < 5; ++u) {
        const float* xr = &xp[(k + u) * 68 + q0];
        float4 xa = *reinterpret_cast<const float4*>(xr);
        float4 xc = *reinterpret_cast<const float4*>(xr + 4);
        float xv[8] = {xa.x, xa.y, xa.z, xa.w, xc.x, xc.y, xc.z, xc.w};
#pragma unroll
        for (int v = 0; v < 5; ++v) {
          int o = u * 5 + v;
          z0 = fmaf(xv[v], K0[o], z0);
          z1 = fmaf(xv[v + 1], K1[o], z1);
          z2 = fmaf(xv[v + 2], K2[o], z2);
          z3 = fmaf(xv[v + 3], K3[o], z3);
        }
      }
      *reinterpret_cast<float4*>(&Sc[co4][((k & 15) << 6) + q0]) =
          make_float4(z0, z1, z2, z3);
    }
    // ---- single lgkm-only barrier: S(t) visible, dump(t-1) reads done;
    // ---- global stores stay in flight ----
    asm volatile("s_waitcnt lgkmcnt(0)" ::: "memory");
    __builtin_amdgcn_s_barrier();
  }
  // ---- epilogue: dump(15) ----
  {
    const int co = 28 + wave;
    float* dst = outb + (((size_t)co) << 12) + ((r0 + 16) << 6);
    const float4* Sp = reinterpret_cast<const float4*>(&S[1][wave][0]);
#pragma unroll
    for (int i = 0; i < 4; ++i) {
      int f4 = (i << 6) + lane;
      int kk = f4 >> 4, q0 = (f4 & 15) << 2;
      unsigned bits = (unsigned)(Rm[16 + kk] >> q0) & 0xFu;
      float4 v = Sp[f4];
      if (!(bits & 1u)) v.x = 0.f;
      if (!(bits & 2u)) v.y = 0.f;
      if (!(bits & 4u)) v.z = 0.f;
      if (!(bits & 8u)) v.w = 0.f;
      *reinterpret_cast<float4*>(dst + (f4 << 2)) = v;
    }
  }
}

extern "C" void kernel_launch(void* const* d_in, const int* in_sizes, int n_in,
                              void* d_out, int out_size, void* d_ws, size_t ws_size,
                              hipStream_t stream) {
  const float* x  = (const float*)d_in[0];
  const float* W1 = (const float*)d_in[1];
  const float* b1 = (const float*)d_in[2];
  const float* W2 = (const float*)d_in[3];
  const float* b2 = (const float*)d_in[4];
  float* out = (float*)d_out;
  float* ws  = (float*)d_ws;
  int B = in_sizes[0] / 4096;  // 1024 images of 64x64x1

  hipLaunchKernelGGL(prep_kernel, dim3(25), dim3(BDIM), 0, stream, W1, b1, W2, b2, ws);
  hipLaunchKernelGGL(main_kernel, dim3(2 * B), dim3(BDIM), 0, stream, x, ws, out);
}

// Round 11
// 188.061 us; speedup vs baseline: 1.1985x; 1.0057x over previous
//
#include <hip/hip_runtime.h>

#define BDIM 256
#define KC_STRIDE 28                  // per (case,co): K[0..24], bias at [25], 2 pad
#define CASE_STRIDE (32 * KC_STRIDE)  // 896 floats per border-case
#define SP 1032                       // S plane stride (16 rows x 64 + 8 pad)

// case index along one axis: 0 (p==0), 1 (p==1), 2 (interior), 3 (p==62), 4 (p==63)
__device__ __forceinline__ int casef(int p) {
  return ((unsigned)(p - 2) < 60u) ? 2 : (p < 2 ? p : p - 59);
}

// ---------------- prep: collapsed 5x5 kernels, layout [case][co][28] ----------------
__global__ __launch_bounds__(BDIM) void prep_kernel(
    const float* __restrict__ W1, const float* __restrict__ b1,
    const float* __restrict__ W2, const float* __restrict__ b2,
    float* __restrict__ ws) {
  __shared__ float Mlds[9 * 9 * 32];
  __shared__ float BvL[9 * 32];
  const int tid = threadIdx.x;
  const int co = tid & 31;
  for (int tap = tid >> 5; tap < 9; tap += 8) {
    float acc[9] = {0.f, 0.f, 0.f, 0.f, 0.f, 0.f, 0.f, 0.f, 0.f};
    float accB = 0.f;
    for (int ci = 0; ci < 64; ++ci) {
      float w2 = W2[(tap * 64 + ci) * 32 + co];
      accB = fmaf(b1[ci], w2, accB);
#pragma unroll
      for (int e = 0; e < 9; ++e) acc[e] = fmaf(W1[e * 64 + ci], w2, acc[e]);
    }
#pragma unroll
    for (int e = 0; e < 9; ++e) Mlds[(tap * 9 + e) * 32 + co] = acc[e];
    BvL[tap * 32 + co] = accB;
  }
  __syncthreads();

  const int a = blockIdx.x / 5, c = blockIdx.x % 5;
  const int dmask[5] = {4, 6, 7, 3, 1};
  const int Da = dmask[a], Dc = dmask[c];
  for (int t = tid; t < CASE_STRIDE; t += BDIM) {
    int cc = t / KC_STRIDE, r = t % KC_STRIDE;
    float s = 0.f;
    if (r < 25) {
      int u = r / 5, v = r % 5;
      for (int di = 0; di < 3; ++di) {
        if (!((Da >> di) & 1)) continue;
        int ei = u - di;
        if ((unsigned)ei > 2u) continue;
        for (int dj = 0; dj < 3; ++dj) {
          if (!((Dc >> dj) & 1)) continue;
          int ej = v - dj;
          if ((unsigned)ej > 2u) continue;
          s += Mlds[((di * 3 + dj) * 9 + ei * 3 + ej) * 32 + cc];
        }
      }
    } else if (r == 25) {
      s = b2[cc];
      for (int di = 0; di < 3; ++di)
        if ((Da >> di) & 1)
          for (int dj = 0; dj < 3; ++dj)
            if ((Dc >> dj) & 1) s += BvL[(di * 3 + dj) * 32 + cc];
    }
    ws[blockIdx.x * CASE_STRIDE + t] = s;
  }
}

// ---- main: R6 champion structure, S cut to 16-row planes -> ~31 KB LDS,
// ---- 5 blocks/CU. Only variable changed vs R6: occupancy. ----
__global__ __launch_bounds__(BDIM) void main_kernel(
    const float* __restrict__ x, const float* __restrict__ ws,
    float* __restrict__ out) {
  const int bb = blockIdx.x;
  const int b = bb >> 1;
  const int r0 = (bb & 1) << 5;  // 0 or 32
  const int tid = threadIdx.x;
  const int lane = tid & 63;
  const int wave = tid >> 6;

  __shared__ __align__(16) float xp[36 * 68];       // rows r0-2..r0+33, cols -2..65
  __shared__ __align__(16) float S[4][SP];          // 4 planes of 16x64 (+pad)
  __shared__ __align__(16) float KiL[CASE_STRIDE];  // interior case (2,2)
  __shared__ unsigned long long Rm[32];
  __shared__ unsigned short aqi[2][224], aqb[2][64];
  __shared__ int nqi_sh[2], nqb_sh[2];

  if (tid < 2) { nqi_sh[tid] = 0; nqb_sh[tid] = 0; }
  float4* xp4 = reinterpret_cast<float4*>(xp);
  for (int i = tid; i < 612; i += BDIM) xp4[i] = make_float4(0.f, 0.f, 0.f, 0.f);
  for (int i = tid; i < CASE_STRIDE; i += BDIM) KiL[i] = ws[12 * CASE_STRIDE + i];
  __syncthreads();

  const float* xb = x + (size_t)b * 4096;
  for (int it = tid; it < 576; it += BDIM) {
    int i = it >> 4, c4 = (it & 15) << 2;
    int r = r0 - 2 + i;
    if ((unsigned)r < 64u) {
      float4 v = *reinterpret_cast<const float4*>(xb + r * 64 + c4);
      float2* d2 = reinterpret_cast<float2*>(&xp[i * 68 + 2 + c4]);
      d2[0] = make_float2(v.x, v.y);
      d2[1] = make_float2(v.z, v.w);
    }
  }
  __syncthreads();

  for (int k = wave; k < 32; k += 4) {
    int pred = (xp[(k + 2) * 68 + 2 + lane] != 0.0f);
    unsigned long long m = __ballot(pred);
    if (lane == 0) Rm[k] = m;
  }
  __syncthreads();

  for (int g = tid; g < 512; g += BDIM) {
    int k = g >> 4, q0 = (g & 15) << 2;
    unsigned bits = (unsigned)(Rm[k] >> q0) & 0xFu;
    if (!bits) continue;
    int h = k >> 4;
    int p = r0 + k;
    bool inter = ((unsigned)(p - 2) < 60u) && ((unsigned)(q0 - 4) <= 52u);
    if (inter) {
      aqi[h][atomicAdd(&nqi_sh[h], 1)] = (unsigned short)g;
    } else {
      aqb[h][atomicAdd(&nqb_sh[h], 1)] = (unsigned short)g;
    }
  }
  __syncthreads();

  const int ni0 = nqi_sh[0], ni1 = nqi_sh[1];
  const int nb0 = nqb_sh[0], nb1 = nqb_sh[1];
  float* outb = out + (size_t)b * (32 * 4096);

  // 16 substages: t -> (channel group cg = t>>1, row half h = t&1)
  for (int t = 0; t < 16; ++t) {
    const int cg = t >> 1, h = t & 1;
    const int ni = h ? ni1 : ni0;
    const int nb = h ? nb1 : nb0;
    // ---- interior quads: item = (quad, co4); K scalar reads from LDS ----
    for (int n = tid; n < ni * 4; n += BDIM) {
      int g = aqi[h][n >> 2];
      int co4 = n & 3;
      int co = (cg << 2) + co4;
      int k = g >> 4, q0 = (g & 15) << 2;
      const float* Kp = &KiL[co * KC_STRIDE];
      float bias = Kp[25];
      float z0 = bias, z1 = bias, z2 = bias, z3 = bias;
#pragma unroll
      for (int u = 0; u < 5; ++u) {
        const float* xr = &xp[(k + u) * 68 + q0];
        float4 xa = *reinterpret_cast<const float4*>(xr);
        float4 xc = *reinterpret_cast<const float4*>(xr + 4);
        float xv[8] = {xa.x, xa.y, xa.z, xa.w, xc.x, xc.y, xc.z, xc.w};
#pragma unroll
        for (int v = 0; v < 5; ++v) {
          float Kv = Kp[u * 5 + v];
          z0 = fmaf(xv[v], Kv, z0);
          z1 = fmaf(xv[v + 1], Kv, z1);
          z2 = fmaf(xv[v + 2], Kv, z2);
          z3 = fmaf(xv[v + 3], Kv, z3);
        }
      }
      *reinterpret_cast<float4*>(&S[co4][((k & 15) << 6) + q0]) =
          make_float4(z0, z1, z2, z3);
    }
    // ---- border quads: per-pixel case, K scalar reads from global (L2-hot) ----
    for (int n = tid; n < nb * 4; n += BDIM) {
      int g = aqb[h][n >> 2];
      int co4 = n & 3;
      int co = (cg << 2) + co4;
      int k = g >> 4, q0 = (g & 15) << 2;
      int p = r0 + k;
      int cp = casef(p);
      const float* K0 = ws + ((cp * 5 + casef(q0)) * 32 + co) * KC_STRIDE;
      const float* K1 = ws + ((cp * 5 + casef(q0 + 1)) * 32 + co) * KC_STRIDE;
      const float* K2 = ws + ((cp * 5 + casef(q0 + 2)) * 32 + co) * KC_STRIDE;
      const float* K3 = ws + ((cp * 5 + casef(q0 + 3)) * 32 + co) * KC_STRIDE;
      float z0 = K0[25], z1 = K1[25], z2 = K2[25], z3 = K3[25];
#pragma unroll
      for (int u = 0; u < 5; ++u) {
        const float* xr = &xp[(k + u) * 68 + q0];
        float4 xa = *reinterpret_cast<const float4*>(xr);
        float4 xc = *reinterpret_cast<const float4*>(xr + 4);
        float xv[8] = {xa.x, xa.y, xa.z, xa.w, xc.x, xc.y, xc.z, xc.w};
#pragma unroll
        for (int v = 0; v < 5; ++v) {
          int o = u * 5 + v;
          z0 = fmaf(xv[v], K0[o], z0);
          z1 = fmaf(xv[v + 1], K1[o], z1);
          z2 = fmaf(xv[v + 2], K2[o], z2);
          z3 = fmaf(xv[v + 3], K3[o], z3);
        }
      }
      *reinterpret_cast<float4*>(&S[co4][((k & 15) << 6) + q0]) =
          make_float4(z0, z1, z2, z3);
    }
    // ---- drain-free barrier: LDS visibility only; stores stay in flight ----
    asm volatile("s_waitcnt lgkmcnt(0)" ::: "memory");
    __builtin_amdgcn_s_barrier();
    // ---- dump: wave w -> plane w (16 rows, 4 KB contiguous), mask here ----
    {
      int co = (cg << 2) + wave;
      float* dst = outb + (((size_t)co) << 12) + ((r0 + (h << 4)) << 6);
      const float4* Sp = reinterpret_cast<const float4*>(&S[wave][0]);
#pragma unroll
      for (int i = 0; i < 4; ++i) {
        int f4 = (i << 6) + lane;
        int kk = f4 >> 4, q0 = (f4 & 15) << 2;
        unsigned bits = (unsigned)(Rm[(h << 4) + kk] >> q0) & 0xFu;
        float4 v = Sp[f4];
        if (!(bits & 1u)) v.x = 0.f;
        if (!(bits & 2u)) v.y = 0.f;
        if (!(bits & 4u)) v.z = 0.f;
        if (!(bits & 8u)) v.w = 0.f;
        *reinterpret_cast<float4*>(dst + (f4 << 2)) = v;
      }
    }
    // ---- WAR barrier before next substage overwrites S ----
    asm volatile("s_waitcnt lgkmcnt(0)" ::: "memory");
    __builtin_amdgcn_s_barrier();
  }
}

extern "C" void kernel_launch(void* const* d_in, const int* in_sizes, int n_in,
                              void* d_out, int out_size, void* d_ws, size_t ws_size,
                              hipStream_t stream) {
  const float* x  = (const float*)d_in[0];
  const float* W1 = (const float*)d_in[1];
  const float* b1 = (const float*)d_in[2];
  const float* W2 = (const float*)d_in[3];
  const float* b2 = (const float*)d_in[4];
  float* out = (float*)d_out;
  float* ws  = (float*)d_ws;
  int B = in_sizes[0] / 4096;  // 1024 images of 64x64x1

  hipLaunchKernelGGL(prep_kernel, dim3(25), dim3(BDIM), 0, stream, W1, b1, W2, b2, ws);
  hipLaunchKernelGGL(main_kernel, dim3(2 * B), dim3(BDIM), 0, stream, x, ws, out);
}

// Round 12
// 172.675 us; speedup vs baseline: 1.3052x; 1.0891x over previous
//
#include <hip/hip_runtime.h>

#define BDIM 256
#define KC_STRIDE 28                  // per (case,co): K[0..24], bias at [25], 2 pad
#define CASE_STRIDE (32 * KC_STRIDE)  // 896 floats per border-case
#define SP 2052                       // S plane stride (floats), padded (2052%32==4)

// case index along one axis: 0 (p==0), 1 (p==1), 2 (interior), 3 (p==62), 4 (p==63)
__device__ __forceinline__ int casef(int p) {
  return ((unsigned)(p - 2) < 60u) ? 2 : (p < 2 ? p : p - 59);
}

// ---------------- prep: collapsed 5x5 kernels, layout [case][co][28] ----------------
__global__ __launch_bounds__(BDIM) void prep_kernel(
    const float* __restrict__ W1, const float* __restrict__ b1,
    const float* __restrict__ W2, const float* __restrict__ b2,
    float* __restrict__ ws) {
  __shared__ float Mlds[9 * 9 * 32];
  __shared__ float BvL[9 * 32];
  const int tid = threadIdx.x;
  const int co = tid & 31;
  for (int tap = tid >> 5; tap < 9; tap += 8) {
    float acc[9] = {0.f, 0.f, 0.f, 0.f, 0.f, 0.f, 0.f, 0.f, 0.f};
    float accB = 0.f;
    for (int ci = 0; ci < 64; ++ci) {
      float w2 = W2[(tap * 64 + ci) * 32 + co];
      accB = fmaf(b1[ci], w2, accB);
#pragma unroll
      for (int e = 0; e < 9; ++e) acc[e] = fmaf(W1[e * 64 + ci], w2, acc[e]);
    }
#pragma unroll
    for (int e = 0; e < 9; ++e) Mlds[(tap * 9 + e) * 32 + co] = acc[e];
    BvL[tap * 32 + co] = accB;
  }
  __syncthreads();

  const int a = blockIdx.x / 5, c = blockIdx.x % 5;
  const int dmask[5] = {4, 6, 7, 3, 1};
  const int Da = dmask[a], Dc = dmask[c];
  for (int t = tid; t < CASE_STRIDE; t += BDIM) {
    int cc = t / KC_STRIDE, r = t % KC_STRIDE;
    float s = 0.f;
    if (r < 25) {
      int u = r / 5, v = r % 5;
      for (int di = 0; di < 3; ++di) {
        if (!((Da >> di) & 1)) continue;
        int ei = u - di;
        if ((unsigned)ei > 2u) continue;
        for (int dj = 0; dj < 3; ++dj) {
          if (!((Dc >> dj) & 1)) continue;
          int ej = v - dj;
          if ((unsigned)ej > 2u) continue;
          s += Mlds[((di * 3 + dj) * 9 + ei * 3 + ej) * 32 + cc];
        }
      }
    } else if (r == 25) {
      s = b2[cc];
      for (int di = 0; di < 3; ++di)
        if ((Da >> di) & 1)
          for (int dj = 0; dj < 3; ++dj)
            if ((Dc >> dj) & 1) s += BvL[(di * 3 + dj) * 32 + cc];
    }
    ws[blockIdx.x * CASE_STRIDE + t] = s;
  }
}

// ---- main: R6 champion; ONLY change = K[26] hoisted to VGPRs (lane-static co4) ----
__global__ __launch_bounds__(BDIM) void main_kernel(
    const float* __restrict__ x, const float* __restrict__ ws,
    float* __restrict__ out) {
  const int bb = blockIdx.x;
  const int b = bb >> 1;
  const int r0 = (bb & 1) << 5;  // 0 or 32
  const int tid = threadIdx.x;
  const int lane = tid & 63;
  const int wave = tid >> 6;

  __shared__ __align__(16) float xp[36 * 68];      // rows r0-2..r0+33, cols -2..65
  __shared__ __align__(16) float S[4 * SP];        // 4 channel-planes of 32x64, padded
  __shared__ __align__(16) float KiL[CASE_STRIDE]; // interior case (2,2)
  __shared__ unsigned long long Rm[32];
  __shared__ unsigned short aq[512];  // interior from 0 up, border from 511 down
  __shared__ int nqi_sh, nqb_sh;

  if (tid == 0) { nqi_sh = 0; nqb_sh = 0; }
  float4* xp4 = reinterpret_cast<float4*>(xp);
  for (int i = tid; i < 612; i += BDIM) xp4[i] = make_float4(0.f, 0.f, 0.f, 0.f);
  for (int i = tid; i < CASE_STRIDE; i += BDIM) KiL[i] = ws[12 * CASE_STRIDE + i];
  __syncthreads();

  const float* xb = x + (size_t)b * 4096;
  for (int it = tid; it < 576; it += BDIM) {
    int i = it >> 4, c4 = (it & 15) << 2;
    int r = r0 - 2 + i;
    if ((unsigned)r < 64u) {
      float4 v = *reinterpret_cast<const float4*>(xb + r * 64 + c4);
      float2* d2 = reinterpret_cast<float2*>(&xp[i * 68 + 2 + c4]);
      d2[0] = make_float2(v.x, v.y);
      d2[1] = make_float2(v.z, v.w);
    }
  }
  __syncthreads();

  for (int k = wave; k < 32; k += 4) {
    int pred = (xp[(k + 2) * 68 + 2 + lane] != 0.0f);
    unsigned long long m = __ballot(pred);
    if (lane == 0) Rm[k] = m;
  }
  __syncthreads();

  for (int g = tid; g < 512; g += BDIM) {
    int k = g >> 4, q0 = (g & 15) << 2;
    unsigned bits = (unsigned)(Rm[k] >> q0) & 0xFu;
    if (!bits) continue;
    int p = r0 + k;
    bool inter = ((unsigned)(p - 2) < 60u) && ((unsigned)(q0 - 4) <= 52u);
    if (inter) {
      int idx = atomicAdd(&nqi_sh, 1);
      aq[idx] = (unsigned short)g;
    } else {
      int idx = atomicAdd(&nqb_sh, 1);
      aq[511 - idx] = (unsigned short)g;
    }
  }
  __syncthreads();

  const int nqi = nqi_sh, nqb = nqb_sh;
  float* outb = out + (size_t)b * (32 * 4096);
  const int co4 = tid & 3;

  for (int s = 0; s < 8; ++s) {
    // ---- hoist this lane's interior kernel into VGPRs (broadcast reads) ----
    const int co_i = (s << 2) + co4;  // lane-static within the stage
    float K[26];
    {
      const float* Kp = &KiL[co_i * KC_STRIDE];
#pragma unroll
      for (int j = 0; j < 26; ++j) K[j] = Kp[j];
    }
    // ---- interior quads: item = (quad, co4); co4 = tid&3 (loop-invariant) ----
    for (int n = tid; n < nqi * 4; n += BDIM) {
      int g = aq[n >> 2];
      int k = g >> 4, q0 = (g & 15) << 2;
      float bias = K[25];
      float z0 = bias, z1 = bias, z2 = bias, z3 = bias;
#pragma unroll
      for (int u = 0; u < 5; ++u) {
        const float* xr = &xp[(k + u) * 68 + q0];
        float4 xa = *reinterpret_cast<const float4*>(xr);
        float4 xc = *reinterpret_cast<const float4*>(xr + 4);
        float xv[8] = {xa.x, xa.y, xa.z, xa.w, xc.x, xc.y, xc.z, xc.w};
#pragma unroll
        for (int v = 0; v < 5; ++v) {
          float Kv = K[u * 5 + v];
          z0 = fmaf(xv[v], Kv, z0);
          z1 = fmaf(xv[v + 1], Kv, z1);
          z2 = fmaf(xv[v + 2], Kv, z2);
          z3 = fmaf(xv[v + 3], Kv, z3);
        }
      }
      *reinterpret_cast<float4*>(&S[co4 * SP + (k << 6) + q0]) =
          make_float4(z0, z1, z2, z3);
    }
    // ---- border quads: per-pixel case, K scalar reads from global (L2-hot) ----
    for (int n = tid; n < nqb * 4; n += BDIM) {
      int g = aq[511 - (n >> 2)];
      int co = (s << 2) + co4;
      int k = g >> 4, q0 = (g & 15) << 2;
      int p = r0 + k;
      int cp = casef(p);
      const float* K0 = ws + ((cp * 5 + casef(q0)) * 32 + co) * KC_STRIDE;
      const float* K1 = ws + ((cp * 5 + casef(q0 + 1)) * 32 + co) * KC_STRIDE;
      const float* K2 = ws + ((cp * 5 + casef(q0 + 2)) * 32 + co) * KC_STRIDE;
      const float* K3 = ws + ((cp * 5 + casef(q0 + 3)) * 32 + co) * KC_STRIDE;
      float z0 = K0[25], z1 = K1[25], z2 = K2[25], z3 = K3[25];
#pragma unroll
      for (int u = 0; u < 5; ++u) {
        const float* xr = &xp[(k + u) * 68 + q0];
        float4 xa = *reinterpret_cast<const float4*>(xr);
        float4 xc = *reinterpret_cast<const float4*>(xr + 4);
        float xv[8] = {xa.x, xa.y, xa.z, xa.w, xc.x, xc.y, xc.z, xc.w};
#pragma unroll
        for (int v = 0; v < 5; ++v) {
          int o = u * 5 + v;
          z0 = fmaf(xv[v], K0[o], z0);
          z1 = fmaf(xv[v + 1], K1[o], z1);
          z2 = fmaf(xv[v + 2], K2[o], z2);
          z3 = fmaf(xv[v + 3], K3[o], z3);
        }
      }
      *reinterpret_cast<float4*>(&S[co4 * SP + (k << 6) + q0]) =
          make_float4(z0, z1, z2, z3);
    }
    // ---- drain-free barrier: LDS visibility only; dump stores stay in flight ----
    asm volatile("s_waitcnt lgkmcnt(0)" ::: "memory");
    __builtin_amdgcn_s_barrier();
    // ---- dump: wave w -> plane w (8 KB contiguous), mask applied here ----
    {
      int co = (s << 2) + wave;
      float* dst = outb + (((size_t)co) << 12) + (r0 << 6);
#pragma unroll
      for (int i = 0; i < 8; ++i) {
        int idx4 = (i << 6) + lane;
        int k = idx4 >> 4, q0 = (idx4 & 15) << 2;
        unsigned bits = (unsigned)(Rm[k] >> q0) & 0xFu;
        float4 v = *reinterpret_cast<const float4*>(&S[wave * SP + (idx4 << 2)]);
        if (!(bits & 1u)) v.x = 0.f;
        if (!(bits & 2u)) v.y = 0.f;
        if (!(bits & 4u)) v.z = 0.f;
        if (!(bits & 8u)) v.w = 0.f;
        *reinterpret_cast<float4*>(dst + (idx4 << 2)) = v;
      }
    }
    // ---- second drain-free barrier: protect S overwrite (WAR) next stage ----
    asm volatile("s_waitcnt lgkmcnt(0)" ::: "memory");
    __builtin_amdgcn_s_barrier();
  }
}

extern "C" void kernel_launch(void* const* d_in, const int* in_sizes, int n_in,
                              void* d_out, int out_size, void* d_ws, size_t ws_size,
                              hipStream_t stream) {
  const float* x  = (const float*)d_in[0];
  const float* W1 = (const float*)d_in[1];
  const float* b1 = (const float*)d_in[2];
  const float* W2 = (const float*)d_in[3];
  const float* b2 = (const float*)d_in[4];
  float* out = (float*)d_out;
  float* ws  = (float*)d_ws;
  int B = in_sizes[0] / 4096;  // 1024 images of 64x64x1

  hipLaunchKernelGGL(prep_kernel, dim3(25), dim3(BDIM), 0, stream, W1, b1, W2, b2, ws);
  hipLaunchKernelGGL(main_kernel, dim3(2 * B), dim3(BDIM), 0, stream, x, ws, out);
}